// Round 2
// baseline (67.067 us; speedup 1.0000x reference)
//
#include <hip/hip_runtime.h>
#include <stdint.h>

// GGML Q8_0 fused dequant + GEMM:  out[16][8192] = x[16][8192] . W^T + bias
// HARNESS NOTE: quantized_weight (uint8 in the reference) arrives as int32,
// one original byte per int32 element (zero-extended). 71,303,168 elements
// = 285.2 MB -> kernel is HBM-bound (~45 us floor).
//
// One block = 256 thr = 4 waves, owns 16 output cols; wave w handles a
// K-quarter (64 Q8 blocks = 64 x mfma_f32_16x16x32_f16).
// Staging: global int32 -> register byte-pack (v_perm) -> LDS (packed raw
// GGML byte layout, 272 B per col-chunk), double buffered per wave.

typedef _Float16 half8  __attribute__((ext_vector_type(8)));
typedef _Float16 half2v __attribute__((ext_vector_type(2)));
typedef float    float4v __attribute__((ext_vector_type(4)));
typedef uint32_t __attribute__((may_alias)) u32a;
typedef uint16_t __attribute__((may_alias)) u16a;
typedef uint4    __attribute__((may_alias)) u4a;
typedef float4v  __attribute__((may_alias)) f4a;

// pack low bytes of 4 int32 into one dword: [x.b0, y.b0, z.b0, w.b0]
// sel byte 0x0C = constant 0x00 on v_perm.
__device__ __forceinline__ uint32_t pack4(uint4 d) {
  uint32_t p01 = __builtin_amdgcn_perm(d.y, d.x, 0x0C0C0400u);
  uint32_t p23 = __builtin_amdgcn_perm(d.w, d.z, 0x04000C0Cu);
  return p01 | p23;
}

// (q ^ 0x80) byte -> fp16 bits 0x6400 | (q+128) == value 1152+q (exact),
// then packed add of -1152 -> exact integer q as fp16.
__device__ __forceinline__ uint32_t mpair(uint32_t t, uint32_t sel) {
  uint32_t d = __builtin_amdgcn_perm(t, 0x64646464u, sel);
  half2v v = __builtin_bit_cast(half2v, d);
  half2v m = __builtin_bit_cast(half2v, (uint32_t)0xE480E480u); // -1152,-1152
  v = v + m;
  return __builtin_bit_cast(uint32_t, v);
}

extern "C" __global__ __launch_bounds__(256, 2)
void q8lin_kernel(const float* __restrict__ x,
                  const int* __restrict__ wq,
                  const float* __restrict__ bias,
                  float* __restrict__ out)
{
  __shared__ __align__(16) unsigned char smem[4 * 8704]; // per-wave 2x4352 B
  __shared__ __align__(16) float redbuf[4][16][16];      // [wave][col][row]

  const int tid  = threadIdx.x;
  const int wv   = tid >> 6;
  const int lane = tid & 63;
  const int c    = lane & 15;   // A-row (batch) and B-col (output col)
  const int ksub = lane >> 4;   // k-group within MFMA
  const int g    = blockIdx.x;  // output cols [g*16, g*16+16)

  // chunk = 16 cols x 8 Q8 blocks = 16 x 272 int32 elems (= packed bytes).
  // pack-unit u (0..271) = 16 int32 -> 16 packed bytes; col = u/17, sub = u%17.
  unsigned soff[5], wb[5];
#pragma unroll
  for (int r = 0; r < 5; ++r) {
    int u = r * 64 + lane; if (u > 271) u = 271;
    int cc = u / 17;
    int uu = u - cc * 17;
    soff[r] = (unsigned)(g * 16 + cc) * 8704u + (unsigned)uu * 16u; // int32 elems
    wb[r]   = (unsigned)u * 16u;                                    // LDS bytes
  }
  const unsigned kelem0 = (unsigned)wv * 2176u; // wave's K-quarter (elems)
  unsigned char* buf0 = smem + wv * 8704;
  unsigned char* buf1 = buf0 + 4352;

  uint4 dg[20] = {};

  auto loadw = [&](int i) {
    const int* bp = wq + (kelem0 + (unsigned)i * 272u);
#pragma unroll
    for (int r = 0; r < 4; ++r)
#pragma unroll
      for (int s2 = 0; s2 < 4; ++s2)
        dg[r * 4 + s2] = *(const u4a*)(bp + soff[r] + s2 * 4);
    if (lane < 16) {
#pragma unroll
      for (int s2 = 0; s2 < 4; ++s2)
        dg[16 + s2] = *(const u4a*)(bp + soff[4] + s2 * 4);
    }
  };

  auto packwrite = [&](unsigned char* bufp) {
#pragma unroll
    for (int r = 0; r < 4; ++r) {
      uint4 pk;
      pk.x = pack4(dg[r * 4 + 0]); pk.y = pack4(dg[r * 4 + 1]);
      pk.z = pack4(dg[r * 4 + 2]); pk.w = pack4(dg[r * 4 + 3]);
      *(u4a*)(bufp + wb[r]) = pk;
    }
    if (lane < 16) {
      uint4 pk;
      pk.x = pack4(dg[16]); pk.y = pack4(dg[17]);
      pk.z = pack4(dg[18]); pk.w = pack4(dg[19]);
      *(u4a*)(bufp + wb[4]) = pk;
    }
  };

  float4v acc = {0.f, 0.f, 0.f, 0.f};

  auto process_chunk = [&](const unsigned char* bufc, int i) {
    const unsigned kabs0 = (unsigned)wv * 2048u + (unsigned)i * 256u;
#pragma unroll
    for (int j = 0; j < 8; ++j) {
      const unsigned blkoff = (unsigned)c * 272u + (unsigned)j * 34u;
      const unsigned short sb = *(const u16a*)(bufc + blkoff); // fp16 scale
      const float dsc = (float)__builtin_bit_cast(_Float16, sb);
      uint32_t q0, q1, q2, q3;
      if ((j & 1) == 0) {
        // quants start at +2 (mod 4): 3 aligned dwords at blkoff+ksub*8
        const unsigned qo = blkoff + (unsigned)ksub * 8u;
        uint32_t d0 = *(const u32a*)(bufc + qo);
        uint32_t d1 = *(const u32a*)(bufc + qo + 4);
        uint32_t d2 = *(const u32a*)(bufc + qo + 8);
        d0 ^= 0x80808080u; d1 ^= 0x80808080u; d2 ^= 0x80808080u;
        q0 = mpair(d0, 0x00070006u);  // bytes b2,b3
        q1 = mpair(d1, 0x00050004u);  // bytes b0,b1
        q2 = mpair(d1, 0x00070006u);
        q3 = mpair(d2, 0x00050004u);
      } else {
        // quants dword-aligned: 2 dwords at blkoff+2+ksub*8
        const unsigned qo = blkoff + 2u + (unsigned)ksub * 8u;
        uint32_t d0 = *(const u32a*)(bufc + qo);
        uint32_t d1 = *(const u32a*)(bufc + qo + 4);
        d0 ^= 0x80808080u; d1 ^= 0x80808080u;
        q0 = mpair(d0, 0x00050004u);
        q1 = mpair(d0, 0x00070006u);
        q2 = mpair(d1, 0x00050004u);
        q3 = mpair(d1, 0x00070006u);
      }
      half8 bfrag;
      { union { half8 h; uint32_t u[4]; } ub;
        ub.u[0] = q0; ub.u[1] = q1; ub.u[2] = q2; ub.u[3] = q3;
        bfrag = ub.h; }

      // A fragment: x[row=c][kabs .. kabs+8) as f16 (RTZ); x stays L2-hot
      const unsigned kabs = kabs0 + (unsigned)j * 32u + (unsigned)ksub * 8u;
      const float* xp = x + (size_t)c * 8192 + kabs;
      float4v f0 = *(const f4a*)xp;
      float4v f1 = *(const f4a*)(xp + 4);
      half8 afrag;
      { union { half8 h; uint32_t u[4]; } ua;
        ua.u[0] = __builtin_bit_cast(uint32_t, __builtin_amdgcn_cvt_pkrtz(f0[0], f0[1]));
        ua.u[1] = __builtin_bit_cast(uint32_t, __builtin_amdgcn_cvt_pkrtz(f0[2], f0[3]));
        ua.u[2] = __builtin_bit_cast(uint32_t, __builtin_amdgcn_cvt_pkrtz(f1[0], f1[1]));
        ua.u[3] = __builtin_bit_cast(uint32_t, __builtin_amdgcn_cvt_pkrtz(f1[2], f1[3]));
        afrag = ua.h; }

      float4v D = __builtin_amdgcn_mfma_f32_16x16x32_f16(
          afrag, bfrag, (float4v){0.f, 0.f, 0.f, 0.f}, 0, 0, 0);
      acc[0] = fmaf(dsc, D[0], acc[0]);
      acc[1] = fmaf(dsc, D[1], acc[1]);
      acc[2] = fmaf(dsc, D[2], acc[2]);
      acc[3] = fmaf(dsc, D[3], acc[3]);
    }
  };

  // T14-shaped pipeline: issue next chunk's loads, compute current from LDS,
  // then pack+write (vmcnt drains there). All per-wave: DS in-order, no barriers.
  loadw(0);
  packwrite(buf0);
#pragma unroll 1
  for (int i = 0; i < 7; ++i) {
    loadw(i + 1);
    process_chunk((i & 1) ? buf1 : buf0, i);
    packwrite(((i + 1) & 1) ? buf1 : buf0);
  }
  process_chunk(buf1, 7);

  // cross-wave reduction: C/D layout col=lane&15, row=(lane>>4)*4+r (m89)
  *(f4a*)(&redbuf[wv][c][ksub * 4]) = acc;
  __syncthreads();
  {
    const int cc2 = tid & 15;
    const int rr  = tid >> 4;
    float s = redbuf[0][cc2][rr] + redbuf[1][cc2][rr]
            + redbuf[2][cc2][rr] + redbuf[3][cc2][rr]
            + bias[g * 16 + cc2];
    out[(size_t)rr * 8192 + (size_t)(g * 16 + cc2)] = s;
  }
}

extern "C" void kernel_launch(void* const* d_in, const int* in_sizes, int n_in,
                              void* d_out, int out_size, void* d_ws, size_t ws_size,
                              hipStream_t stream) {
  const float* x    = (const float*)d_in[0];
  const int*   wq   = (const int*)d_in[1];
  const float* bias = (const float*)d_in[2];
  float*       out  = (float*)d_out;
  (void)in_sizes; (void)n_in; (void)d_ws; (void)ws_size; (void)out_size;
  q8lin_kernel<<<dim3(8192 / 16), dim3(256), 0, stream>>>(x, wq, bias, out);
}